// Round 1
// baseline (9053.162 us; speedup 1.0000x reference)
//
#include <hip/hip_runtime.h>
#include <hip/hip_fp16.h>
#include <cstdint>

// ---------------- sizes ----------------
#define NUM_WORDS 4096
#define MAX_CHARS 16
#define CE 10
#define NF 32
#define WE 250
#define HID 250
#define IN_DIM 282      // 32 + 250
#define KPAD 288        // padded IN_DIM
#define NGATE 1000      // 4*HID
#define NPAD 1024       // padded gate rows
#define TAGS 50

// recurrent weight split: 256 padded K cols = 192 in regs (96 u32) + 64 in LDS (32 u32)
#define KREG_U32 96
#define KLDS_U32 32     // = 8 uint4 groups

typedef _Float16 half2v __attribute__((ext_vector_type(2)));

#ifndef __has_builtin
#define __has_builtin(x) 0
#endif

__device__ __forceinline__ float dot2acc(uint32_t w, uint32_t h, float acc) {
#if __has_builtin(__builtin_amdgcn_fdot2)
  return __builtin_amdgcn_fdot2(__builtin_bit_cast(half2v, w),
                                __builtin_bit_cast(half2v, h), acc, false);
#else
  half2v wv = __builtin_bit_cast(half2v, w);
  half2v hv = __builtin_bit_cast(half2v, h);
  return acc + (float)wv.x * (float)hv.x + (float)wv.y * (float)hv.y;
#endif
}

// ---------------- prep kernels ----------------
__global__ void prep_wt(const float* __restrict__ wih, float* __restrict__ wt) {
  int idx = blockIdx.x * 256 + threadIdx.x;           // over [KPAD][NPAD]
  if (idx >= KPAD * NPAD) return;
  int k = idx >> 10, j = idx & (NPAD - 1);
  wt[idx] = (j < NGATE && k < IN_DIM) ? wih[j * IN_DIM + k] : 0.0f;
}

__global__ void prep_bsum(const float* __restrict__ bih, const float* __restrict__ bhh,
                          float* __restrict__ bsum) {
  int j = blockIdx.x * 256 + threadIdx.x;
  if (j >= NPAD) return;
  bsum[j] = (j < NGATE) ? bih[j] + bhh[j] : 0.0f;
}

// w_hh [1000][250] f32 -> f16x2 packed; cols padded to 256.
// u32 col c (cols 2c,2c+1): c<96 -> wreg[c][row]; else LDS part [(c-96)/4][row][((c-96)&3)]
__global__ void prep_whh(const float* __restrict__ whh, uint32_t* __restrict__ wreg,
                         uint32_t* __restrict__ wlds) {
  int j = blockIdx.x;          // 0..1023 row
  int c = threadIdx.x;         // 0..127 u32 col
  int c0 = 2 * c, c1 = 2 * c + 1;
  float f0 = (j < NGATE && c0 < HID) ? whh[j * HID + c0] : 0.0f;
  float f1 = (j < NGATE && c1 < HID) ? whh[j * HID + c1] : 0.0f;
  uint32_t lo = (uint32_t)__half_as_ushort(__float2half(f0));
  uint32_t hi = (uint32_t)__half_as_ushort(__float2half(f1));
  uint32_t v = lo | (hi << 16);
  if (c < KREG_U32) {
    wreg[c * NPAD + j] = v;
  } else {
    int cc = c - KREG_U32;                 // 0..31
    int cg = cc >> 2, e = cc & 3;
    wlds[((size_t)(cg * NPAD) + j) * 4 + e] = v;
  }
}

__global__ void prep_dwt(const float* __restrict__ dw, float* __restrict__ dwt) {
  int idx = blockIdx.x * 256 + threadIdx.x;    // over [HID][64]
  if (idx >= HID * 64) return;
  int k = idx >> 6, l = idx & 63;
  dwt[idx] = (l < TAGS) ? dw[l * HID + k] : 0.0f;
}

// ---------------- feature kernel: char CNN + word emb -> x[4096][288] ----------------
__global__ void feat_kernel(const int* __restrict__ ci, const int* __restrict__ wi,
                            const float* __restrict__ cemb, const float* __restrict__ wemb,
                            const float* __restrict__ convw, const float* __restrict__ convb,
                            float* __restrict__ x) {
  int w = blockIdx.x;
  int t = threadIdx.x;  // 64
  __shared__ float ce[MAX_CHARS][CE];
  __shared__ float cw[NF * CE * 3];
  for (int i = t; i < MAX_CHARS * CE; i += 64) {
    int ch = i / CE, d = i % CE;
    ce[ch][d] = cemb[ci[w * MAX_CHARS + ch] * CE + d];
  }
  for (int i = t; i < NF * CE * 3; i += 64) cw[i] = convw[i];
  __syncthreads();

  int f = t & 31, hf = t >> 5;
  float mx = -1e30f;
  for (int p = hf * 8; p < hf * 8 + 8; ++p) {
    float s = 0.0f;
    for (int kk = 0; kk < 3; ++kk) {
      int cp = p + kk - 1;
      if (cp < 0 || cp > 15) continue;
      for (int d = 0; d < CE; ++d) s = fmaf(ce[cp][d], cw[f * 30 + d * 3 + kk], s);
    }
    mx = fmaxf(mx, s);
  }
  float other = __shfl_xor(mx, 32, 64);
  mx = fmaxf(mx, other) + convb[f];
  if (t < 32) x[(size_t)w * KPAD + f] = mx;

  int widx = wi[w];
  for (int d = t; d < WE; d += 64) x[(size_t)w * KPAD + 32 + d] = wemb[(size_t)widx * WE + d];
  if (t < KPAD - IN_DIM) x[(size_t)w * KPAD + IN_DIM + t] = 0.0f;
}

// ---------------- pre-gate GEMM: pre[4096][1024] = x[4096][288] * wt[288][1024] + bsum ----
#define GBM 64
#define GBN 64
#define GBK 16
__global__ __launch_bounds__(256) void gemm_pre(const float* __restrict__ x,
                                                const float* __restrict__ wt,
                                                const float* __restrict__ bsum,
                                                float* __restrict__ pre) {
  __shared__ float As[GBK][GBM];
  __shared__ float Bs[GBK][GBN];
  int tid = threadIdx.x;
  int m0 = blockIdx.y * GBM, n0 = blockIdx.x * GBN;
  int tx = tid & 15, ty = tid >> 4;
  float acc[4][4] = {};
  for (int k0 = 0; k0 < KPAD; k0 += GBK) {
    {
      int r = tid >> 2, cq = (tid & 3) * 4;
      float4 av = *(const float4*)(x + (size_t)(m0 + r) * KPAD + k0 + cq);
      As[cq + 0][r] = av.x; As[cq + 1][r] = av.y; As[cq + 2][r] = av.z; As[cq + 3][r] = av.w;
    }
    {
      int r = tid >> 4, c = (tid & 15) * 4;
      float4 bv = *(const float4*)(wt + (size_t)(k0 + r) * NPAD + n0 + c);
      *(float4*)&Bs[r][c] = bv;
    }
    __syncthreads();
#pragma unroll
    for (int k = 0; k < GBK; ++k) {
      float a[4], b[4];
#pragma unroll
      for (int i = 0; i < 4; ++i) a[i] = As[k][ty * 4 + i];
#pragma unroll
      for (int j = 0; j < 4; ++j) b[j] = Bs[k][tx * 4 + j];
#pragma unroll
      for (int i = 0; i < 4; ++i)
#pragma unroll
        for (int j = 0; j < 4; ++j) acc[i][j] = fmaf(a[i], b[j], acc[i][j]);
    }
    __syncthreads();
  }
#pragma unroll
  for (int i = 0; i < 4; ++i) {
    int m = m0 + ty * 4 + i;
#pragma unroll
    for (int j = 0; j < 4; ++j) {
      int n = n0 + tx * 4 + j;
      pre[(size_t)m * NPAD + n] = acc[i][j] + bsum[n];
    }
  }
}

// ---------------- persistent single-block LSTM ----------------
// block 512: thread T owns gate rows T and T+512. Weights: 2x96 u32 f16x2 in VGPRs,
// cols 192..255 in LDS (128KB). h broadcast as half2 from LDS.
__global__ __launch_bounds__(512) void lstm_kernel(const uint32_t* __restrict__ wreg_g,
                                                   const uint32_t* __restrict__ wlds_g,
                                                   const float* __restrict__ pre,
                                                   float* __restrict__ hs) {
  extern __shared__ uint8_t smem[];
  uint4* s_wlds = (uint4*)smem;                              // [8][1024] uint4 = 128KB
  float* s_act = (float*)(smem + 131072);                    // [1024] f32
  uint32_t* s_h2 = (uint32_t*)(smem + 131072 + 4096);        // [128] u32 (256 halves)

  const int T = threadIdx.x;
  const int r1 = T + 512;

  uint32_t w0[KREG_U32], w1[KREG_U32];
#pragma unroll
  for (int c = 0; c < KREG_U32; ++c) {
    w0[c] = wreg_g[c * NPAD + T];
    w1[c] = wreg_g[c * NPAD + r1];
  }
  {
    const uint4* g = (const uint4*)wlds_g;
#pragma unroll
    for (int i = 0; i < 16; ++i) s_wlds[i * 512 + T] = g[i * 512 + T];
  }
  if (T < 32) ((uint4*)s_h2)[T] = make_uint4(0u, 0u, 0u, 0u);
  float cst = 0.0f;
  __syncthreads();

  const bool tanh0 = (T >= 500);          // row T in [500,512) -> g gate
  const bool tanh1 = (r1 < 750);          // row r1 in [512,750) -> g gate

#pragma unroll 1
  for (int t = 0; t < NUM_WORDS; ++t) {
    float p0 = pre[(size_t)t * NPAD + T];
    float p1 = pre[(size_t)t * NPAD + r1];
    float a0 = 0.0f, a1 = 0.0f;
    const uint4* h2v = (const uint4*)s_h2;
#pragma unroll
    for (int c4 = 0; c4 < 24; ++c4) {
      uint4 hv = h2v[c4];
      a0 = dot2acc(w0[c4 * 4 + 0], hv.x, a0);
      a0 = dot2acc(w0[c4 * 4 + 1], hv.y, a0);
      a0 = dot2acc(w0[c4 * 4 + 2], hv.z, a0);
      a0 = dot2acc(w0[c4 * 4 + 3], hv.w, a0);
      a1 = dot2acc(w1[c4 * 4 + 0], hv.x, a1);
      a1 = dot2acc(w1[c4 * 4 + 1], hv.y, a1);
      a1 = dot2acc(w1[c4 * 4 + 2], hv.z, a1);
      a1 = dot2acc(w1[c4 * 4 + 3], hv.w, a1);
    }
#pragma unroll
    for (int cg = 0; cg < 8; ++cg) {
      uint4 hv = h2v[24 + cg];
      uint4 wv0 = s_wlds[cg * 1024 + T];
      uint4 wv1 = s_wlds[cg * 1024 + r1];
      a0 = dot2acc(wv0.x, hv.x, a0);
      a0 = dot2acc(wv0.y, hv.y, a0);
      a0 = dot2acc(wv0.z, hv.z, a0);
      a0 = dot2acc(wv0.w, hv.w, a0);
      a1 = dot2acc(wv1.x, hv.x, a1);
      a1 = dot2acc(wv1.y, hv.y, a1);
      a1 = dot2acc(wv1.z, hv.z, a1);
      a1 = dot2acc(wv1.w, hv.w, a1);
    }
    a0 += p0;
    a1 += p1;
    // sigmoid(x)=1/(1+e^-x); tanh(x)=1-2/(e^{2x}+1)
    float z0 = __expf(tanh0 ? 2.0f * a0 : -a0);
    float inv0 = 1.0f / (1.0f + z0);
    s_act[T] = tanh0 ? 1.0f - 2.0f * inv0 : inv0;
    float z1 = __expf(tanh1 ? 2.0f * a1 : -a1);
    float inv1 = 1.0f / (1.0f + z1);
    s_act[r1] = tanh1 ? 1.0f - 2.0f * inv1 : inv1;
    __syncthreads();
    if (T < HID) {
      float gi = s_act[T], gf = s_act[T + 250], gg = s_act[T + 500], go = s_act[T + 750];
      cst = gf * cst + gi * gg;
      float z2 = __expf(2.0f * cst);
      float th = 1.0f - 2.0f / (1.0f + z2);
      float h = go * th;
      hs[(size_t)t * 256 + T] = h;
      ((__half*)s_h2)[T] = __float2half(h);
    }
    __syncthreads();
  }
}

// ---------------- dense + log_softmax ----------------
__global__ __launch_bounds__(256) void dense_kernel(const float* __restrict__ hs,
                                                    const float* __restrict__ dwt,
                                                    const float* __restrict__ db,
                                                    float* __restrict__ out) {
  int t = blockIdx.x * 4 + (threadIdx.x >> 6);
  int l = threadIdx.x & 63;
  float acc = 0.0f;
  for (int k = 0; k < HID; ++k) acc = fmaf(hs[(size_t)t * 256 + k], dwt[k * 64 + l], acc);
  float logit = acc + ((l < TAGS) ? db[l] : 0.0f);
  float val = (l < TAGS) ? logit : -1e30f;
  float m = val;
#pragma unroll
  for (int off = 32; off; off >>= 1) m = fmaxf(m, __shfl_xor(m, off, 64));
  float e = (l < TAGS) ? __expf(logit - m) : 0.0f;
  float s = e;
#pragma unroll
  for (int off = 32; off; off >>= 1) s += __shfl_xor(s, off, 64);
  if (l < TAGS) out[(size_t)t * TAGS + l] = logit - m - logf(s);
}

// ---------------- launch ----------------
extern "C" void kernel_launch(void* const* d_in, const int* in_sizes, int n_in,
                              void* d_out, int out_size, void* d_ws, size_t ws_size,
                              hipStream_t stream) {
  const int*   ci    = (const int*)d_in[0];
  const int*   wi    = (const int*)d_in[1];
  const float* cemb  = (const float*)d_in[2];
  const float* wemb  = (const float*)d_in[3];
  const float* convw = (const float*)d_in[4];
  const float* convb = (const float*)d_in[5];
  const float* wih   = (const float*)d_in[6];
  const float* whh   = (const float*)d_in[7];
  const float* bih   = (const float*)d_in[8];
  const float* bhh   = (const float*)d_in[9];
  const float* dw    = (const float*)d_in[10];
  const float* db    = (const float*)d_in[11];
  float* out = (float*)d_out;

  uint8_t* ws = (uint8_t*)d_ws;
  size_t off = 0;
  auto alloc = [&](size_t bytes) -> void* {
    void* p = ws + off;
    off += (bytes + 255) & ~(size_t)255;
    return p;
  };
  float*    wt   = (float*)alloc((size_t)KPAD * NPAD * 4);
  float*    bsum = (float*)alloc(NPAD * 4);
  uint32_t* wreg = (uint32_t*)alloc((size_t)KREG_U32 * NPAD * 4);
  uint32_t* wlds = (uint32_t*)alloc((size_t)8 * NPAD * 16);
  float*    dwt  = (float*)alloc((size_t)HID * 64 * 4);
  float*    x    = (float*)alloc((size_t)NUM_WORDS * KPAD * 4);
  float*    pre  = (float*)alloc((size_t)NUM_WORDS * NPAD * 4);
  float*    hs   = (float*)alloc((size_t)NUM_WORDS * 256 * 4);
  (void)ws_size; (void)in_sizes; (void)n_in; (void)out_size;

  prep_wt<<<(KPAD * NPAD + 255) / 256, 256, 0, stream>>>(wih, wt);
  prep_bsum<<<(NPAD + 255) / 256, 256, 0, stream>>>(bih, bhh, bsum);
  prep_whh<<<NPAD, 128, 0, stream>>>(whh, wreg, wlds);
  prep_dwt<<<(HID * 64 + 255) / 256, 256, 0, stream>>>(dw, dwt);
  feat_kernel<<<NUM_WORDS, 64, 0, stream>>>(ci, wi, cemb, wemb, convw, convb, x);
  gemm_pre<<<dim3(NPAD / GBN, NUM_WORDS / GBM), 256, 0, stream>>>(x, wt, bsum, pre);

  size_t smem = 131072 + 4096 + 512;
  hipFuncSetAttribute((const void*)lstm_kernel,
                      hipFuncAttributeMaxDynamicSharedMemorySize, (int)smem);
  lstm_kernel<<<1, 512, smem, stream>>>(wreg, wlds, pre, hs);
  dense_kernel<<<NUM_WORDS / 4, 256, 0, stream>>>(hs, dwt, db, out);
}

// Round 2
// 7603.381 us; speedup vs baseline: 1.1907x; 1.1907x over previous
//
#include <hip/hip_runtime.h>
#include <hip/hip_fp16.h>
#include <cstdint>

// ---------------- sizes ----------------
#define NUM_WORDS 4096
#define MAX_CHARS 16
#define CE 10
#define NF 32
#define WE 250
#define HID 250
#define IN_DIM 282      // 32 + 250
#define KPAD 288        // padded IN_DIM
#define NGATE 1000      // 4*HID
#define NPAD 1024       // padded gate rows
#define TAGS 50

// recurrent weight split: 256 padded K cols = 192 in regs (96 u32) + 64 in LDS (32 u32)
#define KREG_U32 96
#define KLDS_U32 32     // = 8 uint4 groups

typedef _Float16 half2v __attribute__((ext_vector_type(2)));

#ifndef __has_builtin
#define __has_builtin(x) 0
#endif

__device__ __forceinline__ float dot2acc(uint32_t w, uint32_t h, float acc) {
#if __has_builtin(__builtin_amdgcn_fdot2)
  return __builtin_amdgcn_fdot2(__builtin_bit_cast(half2v, w),
                                __builtin_bit_cast(half2v, h), acc, false);
#else
  half2v wv = __builtin_bit_cast(half2v, w);
  half2v hv = __builtin_bit_cast(half2v, h);
  return acc + (float)wv.x * (float)hv.x + (float)wv.y * (float)hv.y;
#endif
}

// ---------------- prep kernels ----------------
__global__ void prep_wt(const float* __restrict__ wih, float* __restrict__ wt) {
  int idx = blockIdx.x * 256 + threadIdx.x;           // over [KPAD][NPAD]
  if (idx >= KPAD * NPAD) return;
  int k = idx >> 10, j = idx & (NPAD - 1);
  wt[idx] = (j < NGATE && k < IN_DIM) ? wih[j * IN_DIM + k] : 0.0f;
}

__global__ void prep_bsum(const float* __restrict__ bih, const float* __restrict__ bhh,
                          float* __restrict__ bsum) {
  int j = blockIdx.x * 256 + threadIdx.x;
  if (j >= NPAD) return;
  bsum[j] = (j < NGATE) ? bih[j] + bhh[j] : 0.0f;
}

// w_hh [1000][250] f32 -> f16x2 packed; cols padded to 256.
// u32 col c (cols 2c,2c+1): c<96 -> wreg[c][row]; else LDS part [(c-96)/4][row][((c-96)&3)]
__global__ void prep_whh(const float* __restrict__ whh, uint32_t* __restrict__ wreg,
                         uint32_t* __restrict__ wlds) {
  int j = blockIdx.x;          // 0..1023 row
  int c = threadIdx.x;         // 0..127 u32 col
  int c0 = 2 * c, c1 = 2 * c + 1;
  float f0 = (j < NGATE && c0 < HID) ? whh[j * HID + c0] : 0.0f;
  float f1 = (j < NGATE && c1 < HID) ? whh[j * HID + c1] : 0.0f;
  uint32_t lo = (uint32_t)__half_as_ushort(__float2half(f0));
  uint32_t hi = (uint32_t)__half_as_ushort(__float2half(f1));
  uint32_t v = lo | (hi << 16);
  if (c < KREG_U32) {
    wreg[c * NPAD + j] = v;
  } else {
    int cc = c - KREG_U32;                 // 0..31
    int cg = cc >> 2, e = cc & 3;
    wlds[((size_t)(cg * NPAD) + j) * 4 + e] = v;
  }
}

__global__ void prep_dwt(const float* __restrict__ dw, float* __restrict__ dwt) {
  int idx = blockIdx.x * 256 + threadIdx.x;    // over [HID][64]
  if (idx >= HID * 64) return;
  int k = idx >> 6, l = idx & 63;
  dwt[idx] = (l < TAGS) ? dw[l * HID + k] : 0.0f;
}

// ---------------- feature kernel: char CNN + word emb -> x[4096][288] ----------------
__global__ void feat_kernel(const int* __restrict__ ci, const int* __restrict__ wi,
                            const float* __restrict__ cemb, const float* __restrict__ wemb,
                            const float* __restrict__ convw, const float* __restrict__ convb,
                            float* __restrict__ x) {
  int w = blockIdx.x;
  int t = threadIdx.x;  // 64
  __shared__ float ce[MAX_CHARS][CE];
  __shared__ float cw[NF * CE * 3];
  for (int i = t; i < MAX_CHARS * CE; i += 64) {
    int ch = i / CE, d = i % CE;
    ce[ch][d] = cemb[ci[w * MAX_CHARS + ch] * CE + d];
  }
  for (int i = t; i < NF * CE * 3; i += 64) cw[i] = convw[i];
  __syncthreads();

  int f = t & 31, hf = t >> 5;
  float mx = -1e30f;
  for (int p = hf * 8; p < hf * 8 + 8; ++p) {
    float s = 0.0f;
    for (int kk = 0; kk < 3; ++kk) {
      int cp = p + kk - 1;
      if (cp < 0 || cp > 15) continue;
      for (int d = 0; d < CE; ++d) s = fmaf(ce[cp][d], cw[f * 30 + d * 3 + kk], s);
    }
    mx = fmaxf(mx, s);
  }
  float other = __shfl_xor(mx, 32, 64);
  mx = fmaxf(mx, other) + convb[f];
  if (t < 32) x[(size_t)w * KPAD + f] = mx;

  int widx = wi[w];
  for (int d = t; d < WE; d += 64) x[(size_t)w * KPAD + 32 + d] = wemb[(size_t)widx * WE + d];
  if (t < KPAD - IN_DIM) x[(size_t)w * KPAD + IN_DIM + t] = 0.0f;
}

// ---------------- pre-gate GEMM: pre[4096][1024] = x[4096][288] * wt[288][1024] + bsum ----
#define GBM 64
#define GBN 64
#define GBK 16
__global__ __launch_bounds__(256) void gemm_pre(const float* __restrict__ x,
                                                const float* __restrict__ wt,
                                                const float* __restrict__ bsum,
                                                float* __restrict__ pre) {
  __shared__ float As[GBK][GBM];
  __shared__ float Bs[GBK][GBN];
  int tid = threadIdx.x;
  int m0 = blockIdx.y * GBM, n0 = blockIdx.x * GBN;
  int tx = tid & 15, ty = tid >> 4;
  float acc[4][4] = {};
  for (int k0 = 0; k0 < KPAD; k0 += GBK) {
    {
      int r = tid >> 2, cq = (tid & 3) * 4;
      float4 av = *(const float4*)(x + (size_t)(m0 + r) * KPAD + k0 + cq);
      As[cq + 0][r] = av.x; As[cq + 1][r] = av.y; As[cq + 2][r] = av.z; As[cq + 3][r] = av.w;
    }
    {
      int r = tid >> 4, c = (tid & 15) * 4;
      float4 bv = *(const float4*)(wt + (size_t)(k0 + r) * NPAD + n0 + c);
      *(float4*)&Bs[r][c] = bv;
    }
    __syncthreads();
#pragma unroll
    for (int k = 0; k < GBK; ++k) {
      float a[4], b[4];
#pragma unroll
      for (int i = 0; i < 4; ++i) a[i] = As[k][ty * 4 + i];
#pragma unroll
      for (int j = 0; j < 4; ++j) b[j] = Bs[k][tx * 4 + j];
#pragma unroll
      for (int i = 0; i < 4; ++i)
#pragma unroll
        for (int j = 0; j < 4; ++j) acc[i][j] = fmaf(a[i], b[j], acc[i][j]);
    }
    __syncthreads();
  }
#pragma unroll
  for (int i = 0; i < 4; ++i) {
    int m = m0 + ty * 4 + i;
#pragma unroll
    for (int j = 0; j < 4; ++j) {
      int n = n0 + tx * 4 + j;
      pre[(size_t)m * NPAD + n] = acc[i][j] + bsum[n];
    }
  }
}

// ---------------- persistent single-block LSTM ----------------
// block 512: thread T owns gate rows T and T+512. Weights: 2x96 u32 f16x2 in VGPRs,
// cols 192..255 in LDS (128KB). h broadcast as half2 from LDS.
// __launch_bounds__(512, 2): 8 waves on 1 CU = exactly 2 waves/EU -> 256-VGPR cap.
// The default heuristic (R0) capped at 128 VGPRs and spilled w0/w1 to scratch
// (~393 KB/step of L2 re-reads -> 5240 cy/step). Forcing 2 waves/EU keeps the
// 192 weight u32 in registers.
__global__ __launch_bounds__(512, 2) void lstm_kernel(const uint32_t* __restrict__ wreg_g,
                                                      const uint32_t* __restrict__ wlds_g,
                                                      const float* __restrict__ pre,
                                                      float* __restrict__ hs) {
  extern __shared__ uint8_t smem[];
  uint4* s_wlds = (uint4*)smem;                              // [8][1024] uint4 = 128KB
  float* s_act = (float*)(smem + 131072);                    // [1024] f32
  uint32_t* s_h2 = (uint32_t*)(smem + 131072 + 4096);        // [128] u32 (256 halves)

  const int T = threadIdx.x;
  const int r1 = T + 512;

  uint32_t w0[KREG_U32], w1[KREG_U32];
#pragma unroll
  for (int c = 0; c < KREG_U32; ++c) {
    w0[c] = wreg_g[c * NPAD + T];
    w1[c] = wreg_g[c * NPAD + r1];
  }
  {
    const uint4* g = (const uint4*)wlds_g;
#pragma unroll
    for (int i = 0; i < 16; ++i) s_wlds[i * 512 + T] = g[i * 512 + T];
  }
  if (T < 32) ((uint4*)s_h2)[T] = make_uint4(0u, 0u, 0u, 0u);
  float cst = 0.0f;
  __syncthreads();

  const bool tanh0 = (T >= 500);          // row T in [500,512) -> g gate
  const bool tanh1 = (r1 < 750);          // row r1 in [512,750) -> g gate

  // software-pipelined pre[t] loads: issue t+1's loads before t's dot-product
  float p0n = pre[(size_t)0 * NPAD + T];
  float p1n = pre[(size_t)0 * NPAD + r1];

#pragma unroll 1
  for (int t = 0; t < NUM_WORDS; ++t) {
    float p0 = p0n;
    float p1 = p1n;
    if (t + 1 < NUM_WORDS) {
      p0n = pre[(size_t)(t + 1) * NPAD + T];
      p1n = pre[(size_t)(t + 1) * NPAD + r1];
    }
    float a0 = 0.0f, a1 = 0.0f;
    const uint4* h2v = (const uint4*)s_h2;
#pragma unroll
    for (int c4 = 0; c4 < 24; ++c4) {
      uint4 hv = h2v[c4];
      a0 = dot2acc(w0[c4 * 4 + 0], hv.x, a0);
      a0 = dot2acc(w0[c4 * 4 + 1], hv.y, a0);
      a0 = dot2acc(w0[c4 * 4 + 2], hv.z, a0);
      a0 = dot2acc(w0[c4 * 4 + 3], hv.w, a0);
      a1 = dot2acc(w1[c4 * 4 + 0], hv.x, a1);
      a1 = dot2acc(w1[c4 * 4 + 1], hv.y, a1);
      a1 = dot2acc(w1[c4 * 4 + 2], hv.z, a1);
      a1 = dot2acc(w1[c4 * 4 + 3], hv.w, a1);
    }
#pragma unroll
    for (int cg = 0; cg < 8; ++cg) {
      uint4 hv = h2v[24 + cg];
      uint4 wv0 = s_wlds[cg * 1024 + T];
      uint4 wv1 = s_wlds[cg * 1024 + r1];
      a0 = dot2acc(wv0.x, hv.x, a0);
      a0 = dot2acc(wv0.y, hv.y, a0);
      a0 = dot2acc(wv0.z, hv.z, a0);
      a0 = dot2acc(wv0.w, hv.w, a0);
      a1 = dot2acc(wv1.x, hv.x, a1);
      a1 = dot2acc(wv1.y, hv.y, a1);
      a1 = dot2acc(wv1.z, hv.z, a1);
      a1 = dot2acc(wv1.w, hv.w, a1);
    }
    a0 += p0;
    a1 += p1;
    // sigmoid(x)=1/(1+e^-x); tanh(x)=1-2/(e^{2x}+1)
    float z0 = __expf(tanh0 ? 2.0f * a0 : -a0);
    float inv0 = 1.0f / (1.0f + z0);
    s_act[T] = tanh0 ? 1.0f - 2.0f * inv0 : inv0;
    float z1 = __expf(tanh1 ? 2.0f * a1 : -a1);
    float inv1 = 1.0f / (1.0f + z1);
    s_act[r1] = tanh1 ? 1.0f - 2.0f * inv1 : inv1;
    __syncthreads();
    if (T < HID) {
      float gi = s_act[T], gf = s_act[T + 250], gg = s_act[T + 500], go = s_act[T + 750];
      cst = gf * cst + gi * gg;
      float z2 = __expf(2.0f * cst);
      float th = 1.0f - 2.0f / (1.0f + z2);
      float h = go * th;
      hs[(size_t)t * 256 + T] = h;
      ((__half*)s_h2)[T] = __float2half(h);
    }
    __syncthreads();
  }
}

// ---------------- dense + log_softmax ----------------
__global__ __launch_bounds__(256) void dense_kernel(const float* __restrict__ hs,
                                                    const float* __restrict__ dwt,
                                                    const float* __restrict__ db,
                                                    float* __restrict__ out) {
  int t = blockIdx.x * 4 + (threadIdx.x >> 6);
  int l = threadIdx.x & 63;
  float acc = 0.0f;
  for (int k = 0; k < HID; ++k) acc = fmaf(hs[(size_t)t * 256 + k], dwt[k * 64 + l], acc);
  float logit = acc + ((l < TAGS) ? db[l] : 0.0f);
  float val = (l < TAGS) ? logit : -1e30f;
  float m = val;
#pragma unroll
  for (int off = 32; off; off >>= 1) m = fmaxf(m, __shfl_xor(m, off, 64));
  float e = (l < TAGS) ? __expf(logit - m) : 0.0f;
  float s = e;
#pragma unroll
  for (int off = 32; off; off >>= 1) s += __shfl_xor(s, off, 64);
  if (l < TAGS) out[(size_t)t * TAGS + l] = logit - m - logf(s);
}

// ---------------- launch ----------------
extern "C" void kernel_launch(void* const* d_in, const int* in_sizes, int n_in,
                              void* d_out, int out_size, void* d_ws, size_t ws_size,
                              hipStream_t stream) {
  const int*   ci    = (const int*)d_in[0];
  const int*   wi    = (const int*)d_in[1];
  const float* cemb  = (const float*)d_in[2];
  const float* wemb  = (const float*)d_in[3];
  const float* convw = (const float*)d_in[4];
  const float* convb = (const float*)d_in[5];
  const float* wih   = (const float*)d_in[6];
  const float* whh   = (const float*)d_in[7];
  const float* bih   = (const float*)d_in[8];
  const float* bhh   = (const float*)d_in[9];
  const float* dw    = (const float*)d_in[10];
  const float* db    = (const float*)d_in[11];
  float* out = (float*)d_out;

  uint8_t* ws = (uint8_t*)d_ws;
  size_t off = 0;
  auto alloc = [&](size_t bytes) -> void* {
    void* p = ws + off;
    off += (bytes + 255) & ~(size_t)255;
    return p;
  };
  float*    wt   = (float*)alloc((size_t)KPAD * NPAD * 4);
  float*    bsum = (float*)alloc(NPAD * 4);
  uint32_t* wreg = (uint32_t*)alloc((size_t)KREG_U32 * NPAD * 4);
  uint32_t* wlds = (uint32_t*)alloc((size_t)8 * NPAD * 16);
  float*    dwt  = (float*)alloc((size_t)HID * 64 * 4);
  float*    x    = (float*)alloc((size_t)NUM_WORDS * KPAD * 4);
  float*    pre  = (float*)alloc((size_t)NUM_WORDS * NPAD * 4);
  float*    hs   = (float*)alloc((size_t)NUM_WORDS * 256 * 4);
  (void)ws_size; (void)in_sizes; (void)n_in; (void)out_size;

  prep_wt<<<(KPAD * NPAD + 255) / 256, 256, 0, stream>>>(wih, wt);
  prep_bsum<<<(NPAD + 255) / 256, 256, 0, stream>>>(bih, bhh, bsum);
  prep_whh<<<NPAD, 128, 0, stream>>>(whh, wreg, wlds);
  prep_dwt<<<(HID * 64 + 255) / 256, 256, 0, stream>>>(dw, dwt);
  feat_kernel<<<NUM_WORDS, 64, 0, stream>>>(ci, wi, cemb, wemb, convw, convb, x);
  gemm_pre<<<dim3(NPAD / GBN, NUM_WORDS / GBM), 256, 0, stream>>>(x, wt, bsum, pre);

  size_t smem = 131072 + 4096 + 512;
  hipFuncSetAttribute((const void*)lstm_kernel,
                      hipFuncAttributeMaxDynamicSharedMemorySize, (int)smem);
  lstm_kernel<<<1, 512, smem, stream>>>(wreg, wlds, pre, hs);
  dense_kernel<<<NUM_WORDS / 4, 256, 0, stream>>>(hs, dwt, db, out);
}